// Round 12
// baseline (142.430 us; speedup 1.0000x reference)
//
#include <hip/hip_runtime.h>

// MMD loss, class-compacted (r12). 4 nodes: memset, k_fused, k_colsum,
// k_pairs(+fold). r12 change: k_fused re-parallelized — wave-per-row
// grid-stride at 768 blocks; rank via per-row atomicAdd on alloc[c] (4096
// atomics / 31 addresses — fine; r11's 96-block two-level rank starved MLP:
// 43us @ 1.8% VALUBusy).
// DO NOT reintroduce: r9 persistent grid-barrier (434us); r5 per-element
// colsum atomics (34MB HBM writes); r2 per-block fences at 6144 grid.
// Math verified absmax 0.0 r1-r11: class bucketing, upper-tri tiles w/ 2x
// off-diag, m@D@m = 2n*sum(sq)-2*||sum x||^2, MFMA C/D map col=lane&31,
// row=(reg&3)+8*(reg>>2)+4*(lane>>5).

#define CMAX 32
#define RCAP 6144      // fixed rows per class region
#define RCHUNK 16

typedef __attribute__((ext_vector_type(8)))  short  short8;
typedef __attribute__((ext_vector_type(8)))  unsigned short ushort8;
typedef __attribute__((ext_vector_type(16))) float  float16;

__device__ inline unsigned short f2bf(float x) {  // fp32 -> bf16 RNE
  unsigned u = __float_as_uint(x);
  return (unsigned short)((u + 0x7FFFu + ((u >> 16) & 1u)) >> 16);
}

// ---- K1: wave-per-row single pass: label + rank + sq + bf16 panel write ----
// Panel layout for class c: base c*RCAP rows; 32-row panels; K-step s holds
// chunk m=2s+hf (cols m*8..m*8+7) of row jr at panel*D + s*512+(hf*32+(jr&31))*8.
__global__ __launch_bounds__(256) void k_fused(
    const float* __restrict__ src, const float* __restrict__ tgt,
    const int* __restrict__ slab, const float* __restrict__ tlabel,
    const int* __restrict__ nsd_p,
    int* alloc, int* srccnt, int* tgtcnt, float* ssum,
    unsigned short* __restrict__ fragbuf,
    float* __restrict__ sqc, float* __restrict__ sgnc,
    int S_total, int T, int D, int C) {
  int lane = threadIdx.x & 63;
  int gwid = (blockIdx.x * 256 + threadIdx.x) >> 6;
  int nwv = (gridDim.x * 256) >> 6;
  int nsd = nsd_p[0];
  int S_use = S_total - nsd;
  int N = S_use + T;

  for (int r = gwid; r < N; r += nwv) {
    int c;
    const float* row;
    bool isSrc = (r < S_use);
    if (isSrc) {
      c = slab[nsd + r];
      row = src + (size_t)(nsd + r) * D;
    } else {
      int t = r - S_use;
      row = tgt + (size_t)t * D;
      float v = (lane < C) ? tlabel[(size_t)t * C + lane] : -3.4e38f;
      int idx = lane;
      for (int o = 32; o > 0; o >>= 1) {
        float ov = __shfl_down(v, o, 64);
        int oi = __shfl_down(idx, o, 64);
        if (ov > v || (ov == v && oi < idx)) { v = ov; idx = oi; }
      }
      c = __shfl(idx, 0, 64);
    }
    int rk;
    if (lane == 0) rk = atomicAdd(&alloc[c], 1);
    rk = __shfl(rk, 0, 64);
    int p = c * RCAP + rk;

    const float4* s4 = (const float4*)row;
    unsigned short* pb = fragbuf + (size_t)(c * RCAP + (rk & ~31)) * D;
    int row32 = rk & 31;
    float s = 0.f;
    for (int m = lane; m < (D >> 3); m += 64) {   // D=512: one iteration
      float4 v0 = s4[m * 2], v1 = s4[m * 2 + 1];
      s += v0.x * v0.x + v0.y * v0.y + v0.z * v0.z + v0.w * v0.w +
           v1.x * v1.x + v1.y * v1.y + v1.z * v1.z + v1.w * v1.w;
      ushort8 h;
      h[0] = f2bf(v0.x); h[1] = f2bf(v0.y); h[2] = f2bf(v0.z); h[3] = f2bf(v0.w);
      h[4] = f2bf(v1.x); h[5] = f2bf(v1.y); h[6] = f2bf(v1.z); h[7] = f2bf(v1.w);
      int st = m >> 1, hf = m & 1;
      *(ushort8*)(pb + st * 512 + (hf * 32 + row32) * 8) = h;
    }
    for (int o = 32; o > 0; o >>= 1) s += __shfl_down(s, o, 64);
    if (lane == 0) {
      sqc[p] = s;
      sgnc[p] = isSrc ? 1.f : -1.f;
      atomicAdd(&ssum[c], s);
      if (isSrc) atomicAdd(&srccnt[c], 1); else atomicAdd(&tgtcnt[c], 1);
    }
  }
}

// ---- K2: per-class column sums from bf16 panels (row-chunk parallel) ----
__global__ __launch_bounds__(256) void k_colsum(
    const unsigned short* __restrict__ fragbuf, const int* __restrict__ cnt,
    float* __restrict__ colsum, int D) {
  int c = blockIdx.x;
  int n = cnt[c];
  int i0 = (int)(((long long)n * blockIdx.y) / gridDim.y);
  int i1 = (int)(((long long)n * (blockIdx.y + 1)) / gridDim.y);
  int tid = threadIdx.x;
  const unsigned short* base = fragbuf + (size_t)c * RCAP * D;
  for (int d = tid; d < D; d += 256) {
    int s = d >> 4, hf = (d >> 3) & 1, e = d & 7;
    int colbase = s * 512 + hf * 256 + e;
    float sum = 0.f;
    for (int i = i0; i < i1; i++) {
      unsigned short v = base[(size_t)(i & ~31) * D + colbase + (i & 31) * 8];
      sum += __uint_as_float((unsigned)v << 16);
    }
    if (sum != 0.f) atomicAdd(&colsum[(size_t)c * D + d], sum);
  }
}

// ---- K3: MFMA pair tiles + inline bw + last-block final fold ----
__global__ __launch_bounds__(256) void k_pairs(
    const unsigned short* __restrict__ fragbuf, const float* __restrict__ sqc,
    const float* __restrict__ sgnc, const int* __restrict__ cnt,
    const int* __restrict__ srccnt, const int* __restrict__ tgtcnt,
    const float* __restrict__ ssum, const float* __restrict__ colsum,
    float* losssum, int* done, float* __restrict__ out, int D, int C) {
  __shared__ int s_tp[CMAX + 1], s_tpr[CMAX], s_n[CMAX];
  __shared__ int lastFlag;
  int tid = threadIdx.x;
  if (tid == 0) {          // redundant per-block tile prefix (31 iters, LDS)
    int tt = 0;
    for (int c = 0; c < C; c++) {
      int n = cnt[c];
      s_n[c] = n; s_tp[c] = tt;
      int tpr = (n + 31) >> 5;
      s_tpr[c] = tpr;
      tt += tpr * (tpr + 1) / 2;
    }
    s_tp[C] = tt;
  }
  __syncthreads();
  int tileTotal = s_tp[C];
  int lane = tid & 63;
  int l31 = lane & 31, half = lane >> 5;
  int wv = blockIdx.x * 4 + (tid >> 6);
  int nwv = gridDim.x * 4;

  for (int t = wv; t < tileTotal; t += nwv) {
    int c = 0;
    while (t >= s_tp[c + 1]) c++;
    int lt = t - s_tp[c], tpr = s_tpr[c], jt = 0;
    while (lt >= tpr - jt) { lt -= tpr - jt; jt++; }
    int kt = jt + lt;
    int n = s_n[c];
    int off = c * RCAP;
    int jbase = jt << 5, kbase = kt << 5;
    float wgt = (jt == kt) ? 1.f : 2.f;

    const unsigned short* fa  = fragbuf + (size_t)(off + jbase) * D + lane * 8;
    const unsigned short* fbp = fragbuf + (size_t)(off + kbase) * D + lane * 8;
    float16 acc = {};
    if (D == 512) {
      #pragma unroll
      for (int s = 0; s < 32; s++) {
        short8 a = *(const short8*)(fa + s * 512);
        short8 b = *(const short8*)(fbp + s * 512);
        acc = __builtin_amdgcn_mfma_f32_32x32x16_bf16(a, b, acc, 0, 0, 0);
      }
    } else {
      for (int s = 0; s < (D >> 4); s++) {
        short8 a = *(const short8*)(fa + s * 512);
        short8 b = *(const short8*)(fbp + s * 512);
        acc = __builtin_amdgcn_mfma_f32_32x32x16_bf16(a, b, acc, 0, 0, 0);
      }
    }

    // inline bandwidth: ns = ||sum x||^2 from colsum (butterfly -> all lanes)
    float ns = 0.f;
    for (int d = lane * 8; d < D; d += 512) {
      float4 u0 = *(const float4*)(colsum + (size_t)c * D + d);
      float4 u1 = *(const float4*)(colsum + (size_t)c * D + d + 4);
      ns += u0.x * u0.x + u0.y * u0.y + u0.z * u0.z + u0.w * u0.w +
            u1.x * u1.x + u1.y * u1.y + u1.z * u1.z + u1.w * u1.w;
    }
    for (int o = 32; o > 0; o >>= 1) ns += __shfl_xor(ns, o, 64);
    float nf = (float)n;
    float S1 = 2.f * nf * ssum[c] - 2.f * ns;   // == m @ Dmat @ m
    float bw = S1 / fmaxf(nf * nf - nf, 1.f);
    bw = (bw > 0.f) ? bw : 1.f;
    float inv0 = 4.f / bw;                      // 1 / (bw * 0.25)

    float sqk = sqc[off + kbase + l31];
    float sgk = sgnc[off + kbase + l31];
    bool kval = (kbase + l31) < n;
    float sqjv = sqc[off + jbase + l31];
    float sgjv = sgnc[off + jbase + l31];
    float contrib = 0.f;
    #pragma unroll
    for (int r = 0; r < 16; r++) {
      int m = (r & 3) + 8 * (r >> 2) + 4 * half;
      float sqj = __shfl(sqjv, m, 64);
      float sgj = __shfl(sgjv, m, 64);
      if (kval && (jbase + m) < n) {
        float d = fmaxf(sqj + sqk - 2.f * acc[r], 0.f);
        float s = inv0, kv = 0.f;
        #pragma unroll
        for (int q = 0; q < 5; q++) { kv += __expf(-d * s); s *= 0.5f; }
        contrib += sgj * sgk * kv;
      }
    }
    contrib *= wgt;
    for (int o = 32; o > 0; o >>= 1) contrib += __shfl_down(contrib, o, 64);
    if (lane == 0) atomicAdd(&losssum[c], contrib);
  }

  // last-block fold -> final scalar (one fence+atomic per BLOCK)
  __syncthreads();
  if (tid == 0) {
    __threadfence();
    int d = atomicAdd(done, 1);
    lastFlag = (d == (int)gridDim.x - 1);
  }
  __syncthreads();
  if (lastFlag && tid < 64) {
    int c = tid;
    float loss = 0.f, cv = 0.f;
    if (c < C && srccnt[c] > 0 && tgtcnt[c] > 0) {
      float nf = (float)cnt[c];
      loss = atomicAdd(&losssum[c], 0.f) / fmaxf(nf * nf, 1.f);  // coherent read
      cv = 1.f;
    }
    for (int o = 32; o > 0; o >>= 1) {
      loss += __shfl_down(loss, o, 64);
      cv   += __shfl_down(cv, o, 64);
    }
    if (tid == 0) out[0] = loss / fmaxf(cv, 1.f);
  }
}

extern "C" void kernel_launch(void* const* d_in, const int* in_sizes, int n_in,
                              void* d_out, int out_size, void* d_ws, size_t ws_size,
                              hipStream_t stream) {
  const float* source = (const float*)d_in[0];
  const float* target = (const float*)d_in[1];
  const int* slab     = (const int*)d_in[2];
  const float* tlabel = (const float*)d_in[3];
  const int* nsd_p    = (const int*)d_in[4];
  float* out = (float*)d_out;

  int S_total = in_sizes[2];
  int D = in_sizes[0] / S_total;   // 512
  int T = in_sizes[1] / D;         // 2048
  int C = in_sizes[3] / T;         // 31
  int NMAX = S_total + T;          // 6144; actual N read on device
  (void)NMAX;

  // workspace layout (4-byte words); zeroed-by-memset region first (tiny)
  int* ws = (int*)d_ws;
  int* alloc    = ws;                     // C  (doubles as final cnt)
  int* srccnt   = alloc + C;              // C
  int* tgtcnt   = srccnt + C;             // C
  float* ssum   = (float*)(tgtcnt + C);   // C
  float* losssum = ssum + C;              // C
  int* done     = (int*)(losssum + C);    // 8
  float* colsum = (float*)(done + 8);     // C*D  (zeroed by memset too)
  int zwords    = 5 * C + 8 + C * D;

  float* sqc    = (float*)(ws + zwords);        // C*RCAP
  float* sgnc   = sqc + (size_t)C * RCAP;       // C*RCAP
  size_t words_used = (size_t)zwords + 2 * (size_t)C * RCAP;
  size_t fw = (words_used + 63) & ~(size_t)63;  // 256B-align fragbuf
  unsigned short* fragbuf = (unsigned short*)(ws + fw);  // C*RCAP*D bf16 (~195MB)

  hipMemsetAsync(d_ws, 0, (size_t)zwords * sizeof(int), stream);

  k_fused<<<768, 256, 0, stream>>>(source, target, slab, tlabel, nsd_p,
                                   alloc, srccnt, tgtcnt, ssum,
                                   fragbuf, sqc, sgnc,
                                   S_total, T, D, C);
  k_colsum<<<dim3(C, RCHUNK), 256, 0, stream>>>(fragbuf, alloc, colsum, D);
  k_pairs<<<208, 256, 0, stream>>>(fragbuf, sqc, sgnc, alloc, srccnt, tgtcnt,
                                   ssum, colsum, losssum, done, out, D, C);
}

// Round 13
// 113.351 us; speedup vs baseline: 1.2565x; 1.2565x over previous
//
#include <hip/hip_runtime.h>

// MMD loss, class-compacted (r13). 4 nodes: memset, k_fused, k_colsum,
// k_pairs(+fold). r13 change: per-class counters padded to ONE 128B cache
// line per class (pc[c*32] = alloc, srcflag, tgtflag, ssum). r12's 54us
// k_fused was ~16K atomic RMWs serialized on ~4 shared cache lines (~30cyc
// each); padding gives 31 parallel atomic streams. srccnt/tgtcnt -> set-once
// flags (load-check + atomicExch, ~62 RMWs total). Row data loads issued
// before the rank atomic to overlap its round trip.
// DO NOT reintroduce: r9 persistent grid-barrier (434us); r5 per-element
// colsum atomics (34MB writes); r2 per-block fences at 6144 grid; r12
// unpadded per-row atomics (54us).
// Math verified absmax 0.0 r1-r12: class bucketing, upper-tri tiles w/ 2x
// off-diag, m@D@m = 2n*sum(sq)-2*||sum x||^2, MFMA C/D map col=lane&31,
// row=(reg&3)+8*(reg>>2)+4*(lane>>5).

#define CMAX 32
#define RCAP 6144      // fixed rows per class region
#define RCHUNK 16
#define PCW 32         // ints per class in padded counter block (128B)

typedef __attribute__((ext_vector_type(8)))  short  short8;
typedef __attribute__((ext_vector_type(8)))  unsigned short ushort8;
typedef __attribute__((ext_vector_type(16))) float  float16;

__device__ inline unsigned short f2bf(float x) {  // fp32 -> bf16 RNE
  unsigned u = __float_as_uint(x);
  return (unsigned short)((u + 0x7FFFu + ((u >> 16) & 1u)) >> 16);
}

// ---- K1: wave-per-row single pass: label + rank + sq + bf16 panel write ----
// Panel layout for class c: base c*RCAP rows; 32-row panels; K-step s holds
// chunk m=2s+hf (cols m*8..m*8+7) of row jr at panel*D + s*512+(hf*32+(jr&31))*8.
__global__ __launch_bounds__(256) void k_fused(
    const float* __restrict__ src, const float* __restrict__ tgt,
    const int* __restrict__ slab, const float* __restrict__ tlabel,
    const int* __restrict__ nsd_p,
    int* pc,                                  // padded per-class counters
    unsigned short* __restrict__ fragbuf,
    float* __restrict__ sqc, float* __restrict__ sgnc,
    int S_total, int T, int D, int C) {
  int lane = threadIdx.x & 63;
  int gwid = (blockIdx.x * 256 + threadIdx.x) >> 6;
  int nwv = (gridDim.x * 256) >> 6;
  int nsd = nsd_p[0];
  int S_use = S_total - nsd;
  int N = S_use + T;

  for (int r = gwid; r < N; r += nwv) {
    int c;
    const float* row;
    bool isSrc = (r < S_use);
    if (isSrc) {
      c = slab[nsd + r];
      row = src + (size_t)(nsd + r) * D;
    } else {
      int t = r - S_use;
      row = tgt + (size_t)t * D;
      float v = (lane < C) ? tlabel[(size_t)t * C + lane] : -3.4e38f;
      int idx = lane;
      for (int o = 32; o > 0; o >>= 1) {
        float ov = __shfl_down(v, o, 64);
        int oi = __shfl_down(idx, o, 64);
        if (ov > v || (ov == v && oi < idx)) { v = ov; idx = oi; }
      }
      c = __shfl(idx, 0, 64);
    }
    const float4* s4 = (const float4*)row;
    int nm = D >> 3;
    float4 v0, v1;
    if (lane < nm) { v0 = s4[lane * 2]; v1 = s4[lane * 2 + 1]; }  // in flight

    int rk;
    if (lane == 0) rk = atomicAdd(&pc[c * PCW], 1);   // own 128B line/class
    rk = __shfl(rk, 0, 64);
    int p = c * RCAP + rk;
    unsigned short* pb = fragbuf + (size_t)(c * RCAP + (rk & ~31)) * D;
    int row32 = rk & 31;

    float s = 0.f;
    if (lane < nm) {
      s += v0.x * v0.x + v0.y * v0.y + v0.z * v0.z + v0.w * v0.w +
           v1.x * v1.x + v1.y * v1.y + v1.z * v1.z + v1.w * v1.w;
      ushort8 h;
      h[0] = f2bf(v0.x); h[1] = f2bf(v0.y); h[2] = f2bf(v0.z); h[3] = f2bf(v0.w);
      h[4] = f2bf(v1.x); h[5] = f2bf(v1.y); h[6] = f2bf(v1.z); h[7] = f2bf(v1.w);
      int st = lane >> 1, hf = lane & 1;
      *(ushort8*)(pb + st * 512 + (hf * 32 + row32) * 8) = h;
    }
    for (int m = lane + 64; m < nm; m += 64) {   // D>512 fallback (not hit)
      float4 w0 = s4[m * 2], w1 = s4[m * 2 + 1];
      s += w0.x * w0.x + w0.y * w0.y + w0.z * w0.z + w0.w * w0.w +
           w1.x * w1.x + w1.y * w1.y + w1.z * w1.z + w1.w * w1.w;
      ushort8 h;
      h[0] = f2bf(w0.x); h[1] = f2bf(w0.y); h[2] = f2bf(w0.z); h[3] = f2bf(w0.w);
      h[4] = f2bf(w1.x); h[5] = f2bf(w1.y); h[6] = f2bf(w1.z); h[7] = f2bf(w1.w);
      int st = m >> 1, hf = m & 1;
      *(ushort8*)(pb + st * 512 + (hf * 32 + row32) * 8) = h;
    }
    for (int o = 32; o > 0; o >>= 1) s += __shfl_down(s, o, 64);
    if (lane == 0) {
      sqc[p] = s;
      sgnc[p] = isSrc ? 1.f : -1.f;
      atomicAdd((float*)&pc[c * PCW + 3], s);           // same line as alloc
      int* flag = &pc[c * PCW + (isSrc ? 1 : 2)];
      if (*(volatile int*)flag == 0) atomicExch(flag, 1);  // set-once
    }
  }
}

// ---- K2: per-class column sums from bf16 panels (row-chunk parallel) ----
__global__ __launch_bounds__(256) void k_colsum(
    const unsigned short* __restrict__ fragbuf, const int* __restrict__ pc,
    float* __restrict__ colsum, int D) {
  int c = blockIdx.x;
  int n = pc[c * PCW];
  int i0 = (int)(((long long)n * blockIdx.y) / gridDim.y);
  int i1 = (int)(((long long)n * (blockIdx.y + 1)) / gridDim.y);
  int tid = threadIdx.x;
  const unsigned short* base = fragbuf + (size_t)c * RCAP * D;
  for (int d = tid; d < D; d += 256) {
    int s = d >> 4, hf = (d >> 3) & 1, e = d & 7;
    int colbase = s * 512 + hf * 256 + e;
    float sum = 0.f;
    for (int i = i0; i < i1; i++) {
      unsigned short v = base[(size_t)(i & ~31) * D + colbase + (i & 31) * 8];
      sum += __uint_as_float((unsigned)v << 16);
    }
    if (sum != 0.f) atomicAdd(&colsum[(size_t)c * D + d], sum);
  }
}

// ---- K3: MFMA pair tiles + inline bw + last-block final fold ----
__global__ __launch_bounds__(256) void k_pairs(
    const unsigned short* __restrict__ fragbuf, const float* __restrict__ sqc,
    const float* __restrict__ sgnc, const int* __restrict__ pc,
    const float* __restrict__ colsum,
    float* losssum, int* done, float* __restrict__ out, int D, int C) {
  __shared__ int s_tp[CMAX + 1], s_tpr[CMAX], s_n[CMAX];
  __shared__ float s_ss[CMAX];
  __shared__ int lastFlag;
  int tid = threadIdx.x;
  if (tid == 0) {          // redundant per-block tile prefix (31 iters, LDS)
    int tt = 0;
    for (int c = 0; c < C; c++) {
      int n = pc[c * PCW];
      s_n[c] = n; s_tp[c] = tt;
      s_ss[c] = ((const float*)pc)[c * PCW + 3];
      int tpr = (n + 31) >> 5;
      s_tpr[c] = tpr;
      tt += tpr * (tpr + 1) / 2;
    }
    s_tp[C] = tt;
  }
  __syncthreads();
  int tileTotal = s_tp[C];
  int lane = tid & 63;
  int l31 = lane & 31, half = lane >> 5;
  int wv = blockIdx.x * 4 + (tid >> 6);
  int nwv = gridDim.x * 4;

  for (int t = wv; t < tileTotal; t += nwv) {
    int c = 0;
    while (t >= s_tp[c + 1]) c++;
    int lt = t - s_tp[c], tpr = s_tpr[c], jt = 0;
    while (lt >= tpr - jt) { lt -= tpr - jt; jt++; }
    int kt = jt + lt;
    int n = s_n[c];
    int off = c * RCAP;
    int jbase = jt << 5, kbase = kt << 5;
    float wgt = (jt == kt) ? 1.f : 2.f;

    const unsigned short* fa  = fragbuf + (size_t)(off + jbase) * D + lane * 8;
    const unsigned short* fbp = fragbuf + (size_t)(off + kbase) * D + lane * 8;
    float16 acc = {};
    if (D == 512) {
      #pragma unroll
      for (int s = 0; s < 32; s++) {
        short8 a = *(const short8*)(fa + s * 512);
        short8 b = *(const short8*)(fbp + s * 512);
        acc = __builtin_amdgcn_mfma_f32_32x32x16_bf16(a, b, acc, 0, 0, 0);
      }
    } else {
      for (int s = 0; s < (D >> 4); s++) {
        short8 a = *(const short8*)(fa + s * 512);
        short8 b = *(const short8*)(fbp + s * 512);
        acc = __builtin_amdgcn_mfma_f32_32x32x16_bf16(a, b, acc, 0, 0, 0);
      }
    }

    // inline bandwidth: ns = ||sum x||^2 from colsum (butterfly -> all lanes)
    float ns = 0.f;
    for (int d = lane * 8; d < D; d += 512) {
      float4 u0 = *(const float4*)(colsum + (size_t)c * D + d);
      float4 u1 = *(const float4*)(colsum + (size_t)c * D + d + 4);
      ns += u0.x * u0.x + u0.y * u0.y + u0.z * u0.z + u0.w * u0.w +
            u1.x * u1.x + u1.y * u1.y + u1.z * u1.z + u1.w * u1.w;
    }
    for (int o = 32; o > 0; o >>= 1) ns += __shfl_xor(ns, o, 64);
    float nf = (float)n;
    float S1 = 2.f * nf * s_ss[c] - 2.f * ns;   // == m @ Dmat @ m
    float bw = S1 / fmaxf(nf * nf - nf, 1.f);
    bw = (bw > 0.f) ? bw : 1.f;
    float inv0 = 4.f / bw;                      // 1 / (bw * 0.25)

    float sqk = sqc[off + kbase + l31];
    float sgk = sgnc[off + kbase + l31];
    bool kval = (kbase + l31) < n;
    float sqjv = sqc[off + jbase + l31];
    float sgjv = sgnc[off + jbase + l31];
    float contrib = 0.f;
    #pragma unroll
    for (int r = 0; r < 16; r++) {
      int m = (r & 3) + 8 * (r >> 2) + 4 * half;
      float sqj = __shfl(sqjv, m, 64);
      float sgj = __shfl(sgjv, m, 64);
      if (kval && (jbase + m) < n) {
        float d = fmaxf(sqj + sqk - 2.f * acc[r], 0.f);
        float s = inv0, kv = 0.f;
        #pragma unroll
        for (int q = 0; q < 5; q++) { kv += __expf(-d * s); s *= 0.5f; }
        contrib += sgj * sgk * kv;
      }
    }
    contrib *= wgt;
    for (int o = 32; o > 0; o >>= 1) contrib += __shfl_down(contrib, o, 64);
    if (lane == 0) atomicAdd(&losssum[c], contrib);
  }

  // last-block fold -> final scalar (one fence+atomic per BLOCK)
  __syncthreads();
  if (tid == 0) {
    __threadfence();
    int d = atomicAdd(done, 1);
    lastFlag = (d == (int)gridDim.x - 1);
  }
  __syncthreads();
  if (lastFlag && tid < 64) {
    int c = tid;
    float loss = 0.f, cv = 0.f;
    if (c < C && pc[c * PCW + 1] > 0 && pc[c * PCW + 2] > 0) {
      float nf = (float)pc[c * PCW];
      loss = atomicAdd(&losssum[c], 0.f) / fmaxf(nf * nf, 1.f);  // coherent read
      cv = 1.f;
    }
    for (int o = 32; o > 0; o >>= 1) {
      loss += __shfl_down(loss, o, 64);
      cv   += __shfl_down(cv, o, 64);
    }
    if (tid == 0) out[0] = loss / fmaxf(cv, 1.f);
  }
}

extern "C" void kernel_launch(void* const* d_in, const int* in_sizes, int n_in,
                              void* d_out, int out_size, void* d_ws, size_t ws_size,
                              hipStream_t stream) {
  const float* source = (const float*)d_in[0];
  const float* target = (const float*)d_in[1];
  const int* slab     = (const int*)d_in[2];
  const float* tlabel = (const float*)d_in[3];
  const int* nsd_p    = (const int*)d_in[4];
  float* out = (float*)d_out;

  int S_total = in_sizes[2];
  int D = in_sizes[0] / S_total;   // 512
  int T = in_sizes[1] / D;         // 2048
  int C = in_sizes[3] / T;         // 31
  int NMAX = S_total + T;          // 6144; actual N read on device
  (void)NMAX;

  // workspace layout (4-byte words); zeroed-by-memset region first (tiny)
  int* ws = (int*)d_ws;
  int* pc       = ws;                     // C*PCW (padded per-class counters)
  float* losssum = (float*)(pc + CMAX * PCW);  // C
  int* done     = (int*)(losssum + C);    // 8
  float* colsum = (float*)(done + 8);     // C*D
  int zwords    = CMAX * PCW + C + 8 + C * D;

  float* sqc    = (float*)(ws + zwords);        // C*RCAP
  float* sgnc   = sqc + (size_t)C * RCAP;       // C*RCAP
  size_t words_used = (size_t)zwords + 2 * (size_t)C * RCAP;
  size_t fw = (words_used + 63) & ~(size_t)63;  // 256B-align fragbuf
  unsigned short* fragbuf = (unsigned short*)(ws + fw);  // C*RCAP*D bf16 (~195MB)

  hipMemsetAsync(d_ws, 0, (size_t)zwords * sizeof(int), stream);

  k_fused<<<768, 256, 0, stream>>>(source, target, slab, tlabel, nsd_p,
                                   pc, fragbuf, sqc, sgnc,
                                   S_total, T, D, C);
  k_colsum<<<dim3(C, RCHUNK), 256, 0, stream>>>(fragbuf, pc, colsum, D);
  k_pairs<<<208, 256, 0, stream>>>(fragbuf, sqc, sgnc, pc, colsum,
                                   losssum, done, out, D, C);
}